// Round 1
// baseline (227.697 us; speedup 1.0000x reference)
//
#include <hip/hip_runtime.h>

// GCN: out = A_hat( relu( A_hat(X) @ W1 + b1 ) @ (W2@Wl) ) + (b2@Wl + bl)
// where A_hat = D^-1/2 (A + I) D^-1/2, aggregations done at 16 features.

constexpr int IN_F  = 16;
constexpr int H1D   = 512;
constexpr int H2D   = 1024;
constexpr int OUTF  = 16;

__global__ void k_init(float* __restrict__ dinv, float* __restrict__ WfT,
                       float* __restrict__ bf, int n) {
  int t = blockIdx.x * blockDim.x + threadIdx.x;
  if (t < n) dinv[t] = 1.0f;                 // self-loop contribution to degree
  if (t < OUTF * H1D) WfT[t] = 0.0f;
  if (t < OUTF) bf[t] = 0.0f;
}

__global__ void k_deg(const int* __restrict__ dst, float* __restrict__ deg, int e) {
  int t = blockIdx.x * blockDim.x + threadIdx.x;
  if (t < e) atomicAdd(&deg[dst[t]], 1.0f);
}

__global__ void k_rsqrt(float* __restrict__ dinv, int n) {
  int t = blockIdx.x * blockDim.x + threadIdx.x;
  if (t < n) dinv[t] = rsqrtf(dinv[t]);      // deg >= 1 always
}

// WfT[o*H1D + j] = sum_k W2[j*H2D + k] * Wl[k*OUTF + o]   (k split into 8 chunks)
__global__ void k_fuseW(const float* __restrict__ W2, const float* __restrict__ Wl,
                        float* __restrict__ WfT) {
  int g = blockIdx.x * blockDim.x + threadIdx.x;   // 512*16*8 = 65536 threads
  int o = g & (OUTF - 1);
  int j = (g >> 4) & (H1D - 1);
  int c = g >> 13;                                  // 0..7
  int k0 = c * (H2D / 8);
  float a0 = 0.f, a1 = 0.f, a2 = 0.f, a3 = 0.f;
  const float* w2r = W2 + (size_t)j * H2D;
  for (int k = k0; k < k0 + H2D / 8; k += 4) {
    a0 = fmaf(w2r[k + 0], Wl[(k + 0) * OUTF + o], a0);
    a1 = fmaf(w2r[k + 1], Wl[(k + 1) * OUTF + o], a1);
    a2 = fmaf(w2r[k + 2], Wl[(k + 2) * OUTF + o], a2);
    a3 = fmaf(w2r[k + 3], Wl[(k + 3) * OUTF + o], a3);
  }
  atomicAdd(&WfT[o * H1D + j], (a0 + a1) + (a2 + a3));
}

__global__ void k_fuseb(const float* __restrict__ b2, const float* __restrict__ Wl,
                        const float* __restrict__ bl, float* __restrict__ bf) {
  int t = threadIdx.x;                 // 128 threads
  int o = t & (OUTF - 1);
  int c = t >> 4;                      // 0..7
  float acc = (c == 0) ? bl[o] : 0.f;
  for (int k = c * (H2D / 8); k < (c + 1) * (H2D / 8); ++k)
    acc = fmaf(b2[k], Wl[k * OUTF + o], acc);
  atomicAdd(&bf[o], acc);
}

// self-loop term (also initializes the buffer): O[i][k] = V[i][k] * dinv[i]^2 (+ bias)
__global__ void k_self(const float* __restrict__ V, const float* __restrict__ dinv,
                       const float* __restrict__ bias, float* __restrict__ O, int n) {
  int t = blockIdx.x * blockDim.x + threadIdx.x;
  if (t < n * 16) {
    int i = t >> 4, k = t & 15;
    float dv = dinv[i];
    float b = bias ? bias[k] : 0.f;
    O[t] = fmaf(V[t], dv * dv, b);
  }
}

// edge scatter: O[dst][k] += V[src][k] * dinv[src]*dinv[dst]
__global__ void k_agg(const float* __restrict__ V, const int* __restrict__ src,
                      const int* __restrict__ dst, const float* __restrict__ dinv,
                      float* __restrict__ O, int e) {
  int t = blockIdx.x * blockDim.x + threadIdx.x;
  if (t < e * 16) {
    int ed = t >> 4, k = t & 15;
    int s = src[ed], d = dst[ed];
    float nrm = dinv[s] * dinv[d];
    atomicAdd(&O[d * 16 + k], V[s * 16 + k] * nrm);
  }
}

// G[i] = relu(Xa[i] @ W1 + b1) @ Wf    -- one wave handles 2 nodes; weights in LDS
__global__ __launch_bounds__(256) void k_mlp(const float* __restrict__ Xa,
                                             const float* __restrict__ W1,
                                             const float* __restrict__ b1,
                                             const float* __restrict__ WfT,
                                             float* __restrict__ G, int n) {
  __shared__ float w1s[IN_F * H1D];   // [k][j], 32 KB
  __shared__ float wfs[OUTF * H1D];   // [o][j], 32 KB
  for (int idx = threadIdx.x; idx < IN_F * H1D; idx += 256) {
    w1s[idx] = W1[idx];
    wfs[idx] = WfT[idx];
  }
  __syncthreads();

  int lane  = threadIdx.x & 63;
  int wid   = (blockIdx.x * blockDim.x + threadIdx.x) >> 6;
  int nw    = (gridDim.x * blockDim.x) >> 6;
  int jbase = lane * 8;

  float bb[8];
#pragma unroll
  for (int jj = 0; jj < 8; ++jj) bb[jj] = b1[jbase + jj];

  for (int i0 = wid * 2; i0 < n; i0 += nw * 2) {
    int i1 = i0 + 1;
    bool has1 = (i1 < n);

    float h0[8], h1[8];
#pragma unroll
    for (int jj = 0; jj < 8; ++jj) { h0[jj] = bb[jj]; h1[jj] = bb[jj]; }

    for (int k = 0; k < IN_F; ++k) {
      float x0 = Xa[i0 * 16 + k];
      float x1 = has1 ? Xa[i1 * 16 + k] : 0.f;
      const float* w = &w1s[k * H1D + jbase];
#pragma unroll
      for (int jj = 0; jj < 8; ++jj) {
        float wv = w[jj];
        h0[jj] = fmaf(x0, wv, h0[jj]);
        h1[jj] = fmaf(x1, wv, h1[jj]);
      }
    }
#pragma unroll
    for (int jj = 0; jj < 8; ++jj) {
      h0[jj] = fmaxf(h0[jj], 0.f);
      h1[jj] = fmaxf(h1[jj], 0.f);
    }

    float a0[16], a1[16];
#pragma unroll
    for (int o = 0; o < OUTF; ++o) { a0[o] = 0.f; a1[o] = 0.f; }
#pragma unroll
    for (int o = 0; o < OUTF; ++o) {
      const float* w = &wfs[o * H1D + jbase];
#pragma unroll
      for (int jj = 0; jj < 8; ++jj) {
        float wv = w[jj];
        a0[o] = fmaf(h0[jj], wv, a0[o]);
        a1[o] = fmaf(h1[jj], wv, a1[o]);
      }
    }
    // full butterfly reduce over 64 lanes (all lanes end with the sums)
#pragma unroll
    for (int o = 0; o < OUTF; ++o) {
#pragma unroll
      for (int m = 1; m < 64; m <<= 1) {
        a0[o] += __shfl_xor(a0[o], m, 64);
        a1[o] += __shfl_xor(a1[o], m, 64);
      }
    }
#pragma unroll
    for (int o = 0; o < OUTF; ++o) {
      if (lane == o) {
        G[i0 * 16 + o] = a0[o];
        if (has1) G[i1 * 16 + o] = a1[o];
      }
    }
  }
}

extern "C" void kernel_launch(void* const* d_in, const int* in_sizes, int n_in,
                              void* d_out, int out_size, void* d_ws, size_t ws_size,
                              hipStream_t stream) {
  (void)n_in; (void)out_size; (void)ws_size;
  const float* X   = (const float*)d_in[0];
  const int*   gr  = (const int*)d_in[1];
  const float* W1  = (const float*)d_in[2];
  const float* b1  = (const float*)d_in[3];
  const float* W2  = (const float*)d_in[4];
  const float* b2  = (const float*)d_in[5];
  const float* Wl  = (const float*)d_in[6];
  const float* bl  = (const float*)d_in[7];

  int n = in_sizes[0] / IN_F;      // 20000
  int e = in_sizes[1] / 2;         // 160000
  const int* src = gr;
  const int* dst = gr + e;

  float* ws   = (float*)d_ws;
  float* dinv = ws;                      // n
  float* Xa   = dinv + n;                // n*16
  float* G    = Xa + (size_t)n * 16;     // n*16
  float* WfT  = G + (size_t)n * 16;      // 16*512
  float* bf   = WfT + OUTF * H1D;        // 16
  float* out  = (float*)d_out;

  const int TPB = 256;
  int nb_n   = (n + TPB - 1) / TPB;
  int nb_e   = (e + TPB - 1) / TPB;
  int nb_n16 = (n * 16 + TPB - 1) / TPB;
  int nb_e16 = (e * 16 + TPB - 1) / TPB;
  int nb_ini = ((n > OUTF * H1D ? n : OUTF * H1D) + TPB - 1) / TPB;

  k_init<<<nb_ini, TPB, 0, stream>>>(dinv, WfT, bf, n);
  k_deg<<<nb_e, TPB, 0, stream>>>(dst, dinv, e);
  k_rsqrt<<<nb_n, TPB, 0, stream>>>(dinv, n);
  k_fuseW<<<(H1D * OUTF * 8) / TPB, TPB, 0, stream>>>(W2, Wl, WfT);
  k_fuseb<<<1, 128, 0, stream>>>(b2, Wl, bl, bf);

  // layer 1 aggregation at 16 features: Xa = A_hat X
  k_self<<<nb_n16, TPB, 0, stream>>>(X, dinv, nullptr, Xa, n);
  k_agg<<<nb_e16, TPB, 0, stream>>>(X, src, dst, dinv, Xa, e);

  // fused MLP: G = relu(Xa W1 + b1) Wf
  k_mlp<<<512, TPB, 0, stream>>>(Xa, W1, b1, WfT, G, n);

  // layer 2 aggregation at 16 features: out = A_hat G + bf
  k_self<<<nb_n16, TPB, 0, stream>>>(G, dinv, bf, out, n);
  k_agg<<<nb_e16, TPB, 0, stream>>>(G, src, dst, dinv, out, e);
}

// Round 2
// 173.654 us; speedup vs baseline: 1.3112x; 1.3112x over previous
//
#include <hip/hip_runtime.h>

// GCN: out = A_hat( relu( A_hat(X) @ W1 + b1 ) @ (W2@Wl) ) + (b2@Wl + bl)
// where A_hat = D^-1/2 (A + I) D^-1/2, aggregations done at 16 features.
// MLP done with per-thread nodes + wave-uniform scalar weight loads (no LDS,
// no cross-lane reduce), j-dimension split into C chunks -> partials -> combine.

constexpr int IN_F  = 16;
constexpr int H1D   = 512;
constexpr int H2D   = 1024;
constexpr int OUTF  = 16;

// t covers max(n, 8192): init dinv, zero WfB/bf, transpose W1 -> W1T[j*16+k]
__global__ void k_init(float* __restrict__ dinv, float* __restrict__ WfB,
                       float* __restrict__ bf, float* __restrict__ W1T,
                       const float* __restrict__ W1, int n) {
  int t = blockIdx.x * blockDim.x + threadIdx.x;
  if (t < n) dinv[t] = 1.0f;                 // self-loop contribution to degree
  if (t < OUTF * H1D) WfB[t] = 0.0f;
  if (t < OUTF) bf[t] = 0.0f;
  if (t < IN_F * H1D) {
    int j = t >> 4, k = t & 15;
    W1T[t] = W1[k * H1D + j];
  }
}

__global__ void k_deg(const int* __restrict__ dst, float* __restrict__ deg, int e) {
  int t = blockIdx.x * blockDim.x + threadIdx.x;
  if (t < e) atomicAdd(&deg[dst[t]], 1.0f);
}

__global__ void k_rsqrt(float* __restrict__ dinv, int n) {
  int t = blockIdx.x * blockDim.x + threadIdx.x;
  if (t < n) dinv[t] = rsqrtf(dinv[t]);      // deg >= 1 always
}

// WfB[j*16 + o] = sum_k W2[j*H2D + k] * Wl[k*OUTF + o]   (k split into 8 chunks)
__global__ void k_fuseW(const float* __restrict__ W2, const float* __restrict__ Wl,
                        float* __restrict__ WfB) {
  int g = blockIdx.x * blockDim.x + threadIdx.x;   // 512*16*8 = 65536 threads
  int o = g & (OUTF - 1);
  int j = (g >> 4) & (H1D - 1);
  int c = g >> 13;                                  // 0..7
  int k0 = c * (H2D / 8);
  float a0 = 0.f, a1 = 0.f, a2 = 0.f, a3 = 0.f;
  const float* w2r = W2 + (size_t)j * H2D;
  for (int k = k0; k < k0 + H2D / 8; k += 4) {
    a0 = fmaf(w2r[k + 0], Wl[(k + 0) * OUTF + o], a0);
    a1 = fmaf(w2r[k + 1], Wl[(k + 1) * OUTF + o], a1);
    a2 = fmaf(w2r[k + 2], Wl[(k + 2) * OUTF + o], a2);
    a3 = fmaf(w2r[k + 3], Wl[(k + 3) * OUTF + o], a3);
  }
  atomicAdd(&WfB[j * OUTF + o], (a0 + a1) + (a2 + a3));
}

__global__ void k_fuseb(const float* __restrict__ b2, const float* __restrict__ Wl,
                        const float* __restrict__ bl, float* __restrict__ bf) {
  int t = threadIdx.x;                 // 128 threads
  int o = t & (OUTF - 1);
  int c = t >> 4;                      // 0..7
  float acc = (c == 0) ? bl[o] : 0.f;
  for (int k = c * (H2D / 8); k < (c + 1) * (H2D / 8); ++k)
    acc = fmaf(b2[k], Wl[k * OUTF + o], acc);
  atomicAdd(&bf[o], acc);
}

// self-loop term (also initializes the buffer): O[i][k] = V[i][k] * dinv[i]^2 (+ bias)
__global__ void k_self(const float* __restrict__ V, const float* __restrict__ dinv,
                       const float* __restrict__ bias, float* __restrict__ O, int n) {
  int t = blockIdx.x * blockDim.x + threadIdx.x;
  if (t < n * 16) {
    int i = t >> 4, k = t & 15;
    float dv = dinv[i];
    float b = bias ? bias[k] : 0.f;
    O[t] = fmaf(V[t], dv * dv, b);
  }
}

// edge scatter: O[dst][k] += V[src][k] * dinv[src]*dinv[dst]
__global__ void k_agg(const float* __restrict__ V, const int* __restrict__ src,
                      const int* __restrict__ dst, const float* __restrict__ dinv,
                      float* __restrict__ O, int e) {
  int t = blockIdx.x * blockDim.x + threadIdx.x;
  if (t < e * 16) {
    int ed = t >> 4, k = t & 15;
    int s = src[ed], d = dst[ed];
    float nrm = dinv[s] * dinv[d];
    atomicAdd(&O[d * 16 + k], V[s * 16 + k] * nrm);
  }
}

// partial MLP: part[c][i][o] = sum_{j in chunk c} relu-path contribution.
// One thread per node; weight rows W1T[j][0..15], WfB[j][0..15] are wave-uniform
// (index from blockIdx.y + loop counter only) -> scalar s_load, SMEM pipe.
__global__ __launch_bounds__(256) void k_mlp_part(const float* __restrict__ Xa,
                                                  const float* __restrict__ W1T,
                                                  const float* __restrict__ b1,
                                                  const float* __restrict__ WfB,
                                                  float* __restrict__ part,
                                                  int n, int jc) {
  int i = blockIdx.x * 256 + threadIdx.x;
  int c = blockIdx.y;
  int j0 = c * jc;
  bool valid = (i < n);
  int is = valid ? i : 0;

  float x[16];
  const float4* xr = (const float4*)(Xa + (size_t)is * 16);
#pragma unroll
  for (int q = 0; q < 4; ++q) {
    float4 v = xr[q];
    x[q * 4 + 0] = v.x; x[q * 4 + 1] = v.y; x[q * 4 + 2] = v.z; x[q * 4 + 3] = v.w;
  }

  float a[16];
#pragma unroll
  for (int o = 0; o < 16; ++o) a[o] = 0.f;

  for (int j = j0; j < j0 + jc; ++j) {
    const float* w1r = &W1T[(size_t)j * 16];   // uniform -> SGPR
    const float* wfr = &WfB[(size_t)j * 16];   // uniform -> SGPR
    float h = b1[j];
#pragma unroll
    for (int k = 0; k < 16; ++k) h = fmaf(x[k], w1r[k], h);
    h = fmaxf(h, 0.f);
#pragma unroll
    for (int o = 0; o < 16; ++o) a[o] = fmaf(h, wfr[o], a[o]);
  }

  if (valid) {
    float4* pr = (float4*)(part + ((size_t)c * n + i) * 16);
#pragma unroll
    for (int q = 0; q < 4; ++q)
      pr[q] = make_float4(a[q * 4 + 0], a[q * 4 + 1], a[q * 4 + 2], a[q * 4 + 3]);
  }
}

// G[t4] = sum_c part[c][t4]  (float4 granularity)
__global__ void k_mlp_comb(const float* __restrict__ part, float* __restrict__ G,
                           int n, int C) {
  int t = blockIdx.x * blockDim.x + threadIdx.x;  // n*4 float4s
  if (t < n * 4) {
    const float4* p = (const float4*)part;
    size_t stride = (size_t)n * 4;
    float4 s = p[t];
    for (int c = 1; c < C; ++c) {
      float4 v = p[(size_t)c * stride + t];
      s.x += v.x; s.y += v.y; s.z += v.z; s.w += v.w;
    }
    ((float4*)G)[t] = s;
  }
}

extern "C" void kernel_launch(void* const* d_in, const int* in_sizes, int n_in,
                              void* d_out, int out_size, void* d_ws, size_t ws_size,
                              hipStream_t stream) {
  (void)n_in; (void)out_size;
  const float* X   = (const float*)d_in[0];
  const int*   gr  = (const int*)d_in[1];
  const float* W1  = (const float*)d_in[2];
  const float* b1  = (const float*)d_in[3];
  const float* W2  = (const float*)d_in[4];
  const float* b2  = (const float*)d_in[5];
  const float* Wl  = (const float*)d_in[6];
  const float* bl  = (const float*)d_in[7];

  int n = in_sizes[0] / IN_F;      // 20000
  int e = in_sizes[1] / 2;         // 160000
  const int* src = gr;
  const int* dst = gr + e;

  float* ws   = (float*)d_ws;
  float* dinv = ws;                        // n
  float* Xa   = dinv + n;                  // n*16
  float* G    = Xa + (size_t)n * 16;       // n*16
  float* WfB  = G + (size_t)n * 16;        // 16*512  (j-major: [j][o])
  float* bf   = WfB + OUTF * H1D;          // 16
  float* W1T  = bf + 16;                   // 16*512  (j-major: [j][k])
  float* part = W1T + IN_F * H1D;          // C*n*16
  float* out  = (float*)d_out;

  size_t used = (size_t)(part - ws) * 4;
  int C = 8;
  while (C > 1 && used + (size_t)C * n * 16 * 4 > ws_size) C >>= 1;
  int jc = H1D / C;

  const int TPB = 256;
  int nb_n   = (n + TPB - 1) / TPB;
  int nb_e   = (e + TPB - 1) / TPB;
  int nb_n16 = (n * 16 + TPB - 1) / TPB;
  int nb_e16 = (e * 16 + TPB - 1) / TPB;
  int nb_n4  = (n * 4 + TPB - 1) / TPB;
  int nb_ini = ((n > OUTF * H1D ? n : OUTF * H1D) + TPB - 1) / TPB;

  k_init<<<nb_ini, TPB, 0, stream>>>(dinv, WfB, bf, W1T, W1, n);
  k_deg<<<nb_e, TPB, 0, stream>>>(dst, dinv, e);
  k_rsqrt<<<nb_n, TPB, 0, stream>>>(dinv, n);
  k_fuseW<<<(H1D * OUTF * 8) / TPB, TPB, 0, stream>>>(W2, Wl, WfB);
  k_fuseb<<<1, 128, 0, stream>>>(b2, Wl, bl, bf);

  // layer 1 aggregation at 16 features: Xa = A_hat X
  k_self<<<nb_n16, TPB, 0, stream>>>(X, dinv, nullptr, Xa, n);
  k_agg<<<nb_e16, TPB, 0, stream>>>(X, src, dst, dinv, Xa, e);

  // fused MLP: G = relu(Xa W1 + b1) Wf, j-chunked partials then combine
  dim3 mg(nb_n, C);
  k_mlp_part<<<mg, TPB, 0, stream>>>(Xa, W1T, b1, WfB, part, n, jc);
  k_mlp_comb<<<nb_n4, TPB, 0, stream>>>(part, G, n, C);

  // layer 2 aggregation at 16 features: out = A_hat G + bf
  k_self<<<nb_n16, TPB, 0, stream>>>(G, dinv, bf, out, n);
  k_agg<<<nb_e16, TPB, 0, stream>>>(G, src, dst, dinv, out, e);
}

// Round 3
// 153.461 us; speedup vs baseline: 1.4837x; 1.1316x over previous
//
#include <hip/hip_runtime.h>

// GCN: out = A_hat( relu( A_hat(X) @ W1 + b1 ) @ (W2@Wl) ) + (b2@Wl + bl)
// where A_hat = D^-1/2 (A + I) D^-1/2, aggregations done at 16 features.
// MLP: per-thread nodes + wave-uniform scalar weight loads (no LDS, no
// cross-lane reduce); j split into C chunks -> partials -> fused combine.
// Round 3: compile-time JC + unroll (s_load pipelining), 4-way h-chain split,
// combine fused with layer-2 self-loop init.

constexpr int IN_F  = 16;
constexpr int H1D   = 512;
constexpr int H2D   = 1024;
constexpr int OUTF  = 16;

// t covers max(n, 8192): init dinv, zero WfB/bf, transpose W1 -> W1T[j*16+k]
__global__ void k_init(float* __restrict__ dinv, float* __restrict__ WfB,
                       float* __restrict__ bf, float* __restrict__ W1T,
                       const float* __restrict__ W1, int n) {
  int t = blockIdx.x * blockDim.x + threadIdx.x;
  if (t < n) dinv[t] = 1.0f;                 // self-loop contribution to degree
  if (t < OUTF * H1D) WfB[t] = 0.0f;
  if (t < OUTF) bf[t] = 0.0f;
  if (t < IN_F * H1D) {
    int j = t >> 4, k = t & 15;
    W1T[t] = W1[k * H1D + j];
  }
}

__global__ void k_deg(const int* __restrict__ dst, float* __restrict__ deg, int e) {
  int t = blockIdx.x * blockDim.x + threadIdx.x;
  if (t < e) atomicAdd(&deg[dst[t]], 1.0f);
}

__global__ void k_rsqrt(float* __restrict__ dinv, int n) {
  int t = blockIdx.x * blockDim.x + threadIdx.x;
  if (t < n) dinv[t] = rsqrtf(dinv[t]);      // deg >= 1 always
}

// WfB[j*16 + o] = sum_k W2[j*H2D + k] * Wl[k*OUTF + o]   (k split into 8 chunks)
__global__ void k_fuseW(const float* __restrict__ W2, const float* __restrict__ Wl,
                        float* __restrict__ WfB) {
  int g = blockIdx.x * blockDim.x + threadIdx.x;   // 512*16*8 = 65536 threads
  int o = g & (OUTF - 1);
  int j = (g >> 4) & (H1D - 1);
  int c = g >> 13;                                  // 0..7
  int k0 = c * (H2D / 8);
  float a0 = 0.f, a1 = 0.f, a2 = 0.f, a3 = 0.f;
  const float* w2r = W2 + (size_t)j * H2D;
  for (int k = k0; k < k0 + H2D / 8; k += 4) {
    a0 = fmaf(w2r[k + 0], Wl[(k + 0) * OUTF + o], a0);
    a1 = fmaf(w2r[k + 1], Wl[(k + 1) * OUTF + o], a1);
    a2 = fmaf(w2r[k + 2], Wl[(k + 2) * OUTF + o], a2);
    a3 = fmaf(w2r[k + 3], Wl[(k + 3) * OUTF + o], a3);
  }
  atomicAdd(&WfB[j * OUTF + o], (a0 + a1) + (a2 + a3));
}

__global__ void k_fuseb(const float* __restrict__ b2, const float* __restrict__ Wl,
                        const float* __restrict__ bl, float* __restrict__ bf) {
  int t = threadIdx.x;                 // 128 threads
  int o = t & (OUTF - 1);
  int c = t >> 4;                      // 0..7
  float acc = (c == 0) ? bl[o] : 0.f;
  for (int k = c * (H2D / 8); k < (c + 1) * (H2D / 8); ++k)
    acc = fmaf(b2[k], Wl[k * OUTF + o], acc);
  atomicAdd(&bf[o], acc);
}

// self-loop init (layer 1): Xa[i][k] = X[i][k] * dinv[i]^2
__global__ void k_self(const float* __restrict__ V, const float* __restrict__ dinv,
                       float* __restrict__ O, int n) {
  int t = blockIdx.x * blockDim.x + threadIdx.x;
  if (t < n * 16) {
    int i = t >> 4;
    float dv = dinv[i];
    O[t] = V[t] * dv * dv;
  }
}

// edge scatter: O[dst][k] += V[src][k] * dinv[src]*dinv[dst]
__global__ void k_agg(const float* __restrict__ V, const int* __restrict__ src,
                      const int* __restrict__ dst, const float* __restrict__ dinv,
                      float* __restrict__ O, int e) {
  int t = blockIdx.x * blockDim.x + threadIdx.x;
  if (t < e * 16) {
    int ed = t >> 4, k = t & 15;
    int s = src[ed], d = dst[ed];
    float nrm = dinv[s] * dinv[d];
    atomicAdd(&O[d * 16 + k], V[s * 16 + k] * nrm);
  }
}

// partial MLP: part[c][i][o] = sum_{j in chunk c} relu(...)-path contribution.
// One thread per node; weight rows are wave-uniform -> s_load (SMEM pipe).
// JC compile-time so the unrolled loop software-pipelines the s_loads.
template <int JC>
__global__ __launch_bounds__(256) void k_mlp_part(const float* __restrict__ Xa,
                                                  const float* __restrict__ W1T,
                                                  const float* __restrict__ b1,
                                                  const float* __restrict__ WfB,
                                                  float* __restrict__ part, int n) {
  int i = blockIdx.x * 256 + threadIdx.x;
  int c = blockIdx.y;
  bool valid = (i < n);
  int is = valid ? i : 0;

  float x[16];
  const float4* xr = (const float4*)(Xa + (size_t)is * 16);
#pragma unroll
  for (int q = 0; q < 4; ++q) {
    float4 v = xr[q];
    x[q * 4 + 0] = v.x; x[q * 4 + 1] = v.y; x[q * 4 + 2] = v.z; x[q * 4 + 3] = v.w;
  }

  float a[16];
#pragma unroll
  for (int o = 0; o < 16; ++o) a[o] = 0.f;

  const float* w1p = W1T + (size_t)c * JC * 16;   // uniform -> SGPR base
  const float* wfp = WfB + (size_t)c * JC * 16;
  const float* b1p = b1 + (size_t)c * JC;

#pragma unroll 4
  for (int jj = 0; jj < JC; ++jj) {
    const float* w1r = w1p + jj * 16;
    const float* wfr = wfp + jj * 16;
    float h0 = b1p[jj], h1 = 0.f, h2 = 0.f, h3 = 0.f;
#pragma unroll
    for (int k = 0; k < 4; ++k) {
      h0 = fmaf(x[k +  0], w1r[k +  0], h0);
      h1 = fmaf(x[k +  4], w1r[k +  4], h1);
      h2 = fmaf(x[k +  8], w1r[k +  8], h2);
      h3 = fmaf(x[k + 12], w1r[k + 12], h3);
    }
    float h = fmaxf((h0 + h1) + (h2 + h3), 0.f);
#pragma unroll
    for (int o = 0; o < 16; ++o) a[o] = fmaf(h, wfr[o], a[o]);
  }

  if (valid) {
    float4* pr = (float4*)(part + ((size_t)c * n + i) * 16);
#pragma unroll
    for (int q = 0; q < 4; ++q)
      pr[q] = make_float4(a[q * 4 + 0], a[q * 4 + 1], a[q * 4 + 2], a[q * 4 + 3]);
  }
}

// G[t4] = sum_c part[c][t4]; out[t4] = G[t4]*dinv[i]^2 + bf   (layer-2 self init)
__global__ void k_comb_self(const float* __restrict__ part, const float* __restrict__ dinv,
                            const float* __restrict__ bf, float* __restrict__ G,
                            float* __restrict__ out, int n, int C) {
  int t = blockIdx.x * blockDim.x + threadIdx.x;  // n*4 float4s
  if (t < n * 4) {
    const float4* p = (const float4*)part;
    size_t stride = (size_t)n * 4;
    float4 s = p[t];
    for (int c = 1; c < C; ++c) {
      float4 v = p[(size_t)c * stride + t];
      s.x += v.x; s.y += v.y; s.z += v.z; s.w += v.w;
    }
    ((float4*)G)[t] = s;
    int i = t >> 2, q = t & 3;
    float dv = dinv[i]; dv *= dv;
    float4 b = ((const float4*)bf)[q];
    float4 o = make_float4(fmaf(s.x, dv, b.x), fmaf(s.y, dv, b.y),
                           fmaf(s.z, dv, b.z), fmaf(s.w, dv, b.w));
    ((float4*)out)[t] = o;
  }
}

extern "C" void kernel_launch(void* const* d_in, const int* in_sizes, int n_in,
                              void* d_out, int out_size, void* d_ws, size_t ws_size,
                              hipStream_t stream) {
  (void)n_in; (void)out_size;
  const float* X   = (const float*)d_in[0];
  const int*   gr  = (const int*)d_in[1];
  const float* W1  = (const float*)d_in[2];
  const float* b1  = (const float*)d_in[3];
  const float* W2  = (const float*)d_in[4];
  const float* b2  = (const float*)d_in[5];
  const float* Wl  = (const float*)d_in[6];
  const float* bl  = (const float*)d_in[7];

  int n = in_sizes[0] / IN_F;      // 20000
  int e = in_sizes[1] / 2;         // 160000
  const int* src = gr;
  const int* dst = gr + e;

  float* ws   = (float*)d_ws;
  float* dinv = ws;                        // n
  float* Xa   = dinv + n;                  // n*16
  float* G    = Xa + (size_t)n * 16;       // n*16
  float* WfB  = G + (size_t)n * 16;        // 16*512  (j-major: [j][o])
  float* bf   = WfB + OUTF * H1D;          // 16
  float* W1T  = bf + 16;                   // 16*512  (j-major: [j][k])
  float* part = W1T + IN_F * H1D;          // C*n*16
  float* out  = (float*)d_out;

  size_t used = (size_t)(part - ws) * 4;
  int C = 8;
  while (C > 1 && used + (size_t)C * n * 16 * 4 > ws_size) C >>= 1;

  const int TPB = 256;
  int nb_n   = (n + TPB - 1) / TPB;
  int nb_e   = (e + TPB - 1) / TPB;
  int nb_n16 = (n * 16 + TPB - 1) / TPB;
  int nb_e16 = (e * 16 + TPB - 1) / TPB;
  int nb_n4  = (n * 4 + TPB - 1) / TPB;
  int nb_ini = ((n > OUTF * H1D ? n : OUTF * H1D) + TPB - 1) / TPB;

  k_init<<<nb_ini, TPB, 0, stream>>>(dinv, WfB, bf, W1T, W1, n);
  k_deg<<<nb_e, TPB, 0, stream>>>(dst, dinv, e);
  k_rsqrt<<<nb_n, TPB, 0, stream>>>(dinv, n);
  k_fuseW<<<(H1D * OUTF * 8) / TPB, TPB, 0, stream>>>(W2, Wl, WfB);
  k_fuseb<<<1, 128, 0, stream>>>(b2, Wl, bl, bf);

  // layer 1 aggregation at 16 features: Xa = A_hat X
  k_self<<<nb_n16, TPB, 0, stream>>>(X, dinv, Xa, n);
  k_agg<<<nb_e16, TPB, 0, stream>>>(X, src, dst, dinv, Xa, e);

  // fused MLP: G = relu(Xa W1 + b1) Wf, j-chunked partials then fused combine
  dim3 mg(nb_n, C);
  switch (C) {
    case 8: k_mlp_part<H1D / 8><<<mg, TPB, 0, stream>>>(Xa, W1T, b1, WfB, part, n); break;
    case 4: k_mlp_part<H1D / 4><<<mg, TPB, 0, stream>>>(Xa, W1T, b1, WfB, part, n); break;
    case 2: k_mlp_part<H1D / 2><<<mg, TPB, 0, stream>>>(Xa, W1T, b1, WfB, part, n); break;
    default: k_mlp_part<H1D><<<mg, TPB, 0, stream>>>(Xa, W1T, b1, WfB, part, n); break;
  }
  // combine partials -> G, and write layer-2 self-loop term (+bias) to out
  k_comb_self<<<nb_n4, TPB, 0, stream>>>(part, dinv, bf, G, out, n, C);

  // layer 2 edge aggregation
  k_agg<<<nb_e16, TPB, 0, stream>>>(G, src, dst, dinv, out, e);
}